// Round 7
// baseline (961.840 us; speedup 1.0000x reference)
//
#include <hip/hip_runtime.h>
#include <hip/hip_bf16.h>

#define BB 64
#define NN 50
#define TT 30
#define EE 300
#define FN 400
#define AA 200
#define GG 400

typedef __attribute__((ext_vector_type(8))) short bf16x8;
typedef __attribute__((ext_vector_type(4))) float f32x4;

// ---------------------------------------------------------------------------
// Prep kernels (one-time, tiny)
// ---------------------------------------------------------------------------
__global__ void k_pack_whh(const float* __restrict__ Whh, float* __restrict__ Wpack) {
  int idx = blockIdx.x * 256 + threadIdx.x;
  if (idx < 8 * 400 * 150) {
    int jl = idx % 150;
    int g = (idx / 150) % 400;
    int gc = idx / (150 * 400);
    int gate = jl / 50, gl = jl - gate * 50;
    int j = gate * 400 + gc * 50 + gl;
    Wpack[idx] = Whh[j * 400 + g];
  }
}

// word_emb fp32 [50000][300] -> bf16 [50000][320] (zero pad cols 300..319)
__global__ void k_prep_emb(const float* __restrict__ w, __hip_bfloat16* __restrict__ o) {
  long i = (long)blockIdx.x * 256 + threadIdx.x;
  if (i < (long)50000 * 320) {
    int row = (int)(i / 320), c = (int)(i % 320);
    o[i] = __float2bfloat16(c < EE ? w[(long)row * EE + c] : 0.f);
  }
}

// conv_w fp32 [3][300][400] (k,e,f) -> WT bf16 [448 f][960 k] (zero padded)
__global__ void k_prep_wt(const float* __restrict__ cw, __hip_bfloat16* __restrict__ o) {
  int i = blockIdx.x * 256 + threadIdx.x;
  if (i < 448 * 960) {
    int f = i / 960, kk = i % 960;
    int ko = kk / 320, e = kk % 320;
    float val = (f < FN && e < EE) ? cw[(ko * EE + e) * FN + f] : 0.f;
    o[i] = __float2bfloat16(val);
  }
}

// v fp32 [400 f][200 a] -> vT bf16 [224 a][416 f] (zero padded)
__global__ void k_prep_v(const float* __restrict__ v, __hip_bfloat16* __restrict__ o) {
  int i = blockIdx.x * 256 + threadIdx.x;
  if (i < 224 * 416) {
    int a = i / 416, f = i % 416;
    o[i] = __float2bfloat16((a < AA && f < FN) ? v[f * AA + a] : 0.f);
  }
}

__global__ void k_prep_qvb(const float* __restrict__ q, const float* __restrict__ vb,
                           float* __restrict__ qp, float* __restrict__ vbp) {
  int i = threadIdx.x;
  if (i < 224) {
    qp[i]  = i < AA ? q[i]  : 0.f;
    vbp[i] = i < AA ? vb[i] : 0.f;
  }
}

// W_ih fp32 [1200 j][400 f] -> bf16 [1344 j][416 f] zero-padded
__global__ void k_prep_wih(const float* __restrict__ w, __hip_bfloat16* __restrict__ o) {
  int i = blockIdx.x * 256 + threadIdx.x;
  if (i < 1344 * 416) {
    int j = i / 416, f = i % 416;
    o[i] = __float2bfloat16((j < 1200 && f < 400) ? w[j * 400 + f] : 0.f);
  }
}

// ---------------------------------------------------------------------------
// K_CONV: bf16 MFMA implicit-GEMM conv1d(K=3,pad=1) + bias + ReLU.
// ---------------------------------------------------------------------------
__global__ __launch_bounds__(512) void k_conv(
    const int* __restrict__ title, const __hip_bfloat16* __restrict__ emb,
    const __hip_bfloat16* __restrict__ WT, const float* __restrict__ conv_b,
    __hip_bfloat16* __restrict__ C)
{
  __shared__ __align__(16) ushort Alds[128 * 40];
  __shared__ __align__(16) ushort Blds[448 * 40];
  __shared__ int words[120];
  const int g = blockIdx.x;
  const int tid = threadIdx.x;
  const int lane = tid & 63;
  const int wid = tid >> 6;
  const int wm = wid >> 2;
  const int wn = wid & 3;
  const int l15 = lane & 15;
  const int l4 = lane >> 4;

  if (tid < 120) words[tid] = title[g * 120 + tid];

  f32x4 acc[4][7];
  {
    float bias[7];
#pragma unroll
    for (int nt = 0; nt < 7; ++nt) {
      int f = wn * 112 + nt * 16 + l15;
      bias[nt] = (f < FN) ? conv_b[f] : 0.f;
    }
#pragma unroll
    for (int mt = 0; mt < 4; ++mt)
#pragma unroll
      for (int nt = 0; nt < 7; ++nt) {
        acc[mt][nt][0] = bias[nt]; acc[mt][nt][1] = bias[nt];
        acc[mt][nt][2] = bias[nt]; acc[mt][nt][3] = bias[nt];
      }
  }
  __syncthreads();

  const int ar = tid >> 2, ac = tid & 3;
  const int ati = ar >> 5, at = ar & 31;

  for (int ko = 0; ko < 3; ++ko) {
    int w = at + ko - 1;
    const bool valid = (w >= 0 && w < TT);
    const ushort* asrc = valid ? (const ushort*)emb + (size_t)words[ati * 30 + w] * 320
                               : (const ushort*)emb;
    for (int ks = 0; ks < 10; ++ks) {
      uint4 av = make_uint4(0u, 0u, 0u, 0u);
      if (valid) av = *(const uint4*)(asrc + ks * 32 + ac * 8);
      *(uint4*)(&Alds[ar * 40 + ac * 8]) = av;
      for (int idx = tid; idx < 1792; idx += 512) {
        int f = idx >> 2, c = idx & 3;
        *(uint4*)(&Blds[f * 40 + c * 8]) =
            *(const uint4*)((const ushort*)WT + f * 960 + ko * 320 + ks * 32 + c * 8);
      }
      __syncthreads();
      bf16x8 af[4];
#pragma unroll
      for (int mt = 0; mt < 4; ++mt)
        af[mt] = *(const bf16x8*)(&Alds[(wm * 64 + mt * 16 + l15) * 40 + l4 * 8]);
#pragma unroll
      for (int nt = 0; nt < 7; ++nt) {
        bf16x8 bfr = *(const bf16x8*)(&Blds[(wn * 112 + nt * 16 + l15) * 40 + l4 * 8]);
#pragma unroll
        for (int mt = 0; mt < 4; ++mt)
          acc[mt][nt] = __builtin_amdgcn_mfma_f32_16x16x32_bf16(af[mt], bfr, acc[mt][nt], 0, 0, 0);
      }
      __syncthreads();
    }
  }

#pragma unroll
  for (int mt = 0; mt < 4; ++mt) {
    int rowb = wm * 64 + mt * 16 + l4 * 4;
    int ti = rowb >> 5;
    int tb = rowb & 31;
#pragma unroll
    for (int nt = 0; nt < 7; ++nt) {
      int f = wn * 112 + nt * 16 + l15;
      if (f < 416) {
#pragma unroll
        for (int r = 0; r < 4; ++r) {
          int t = tb + r;
          if (t < TT) {
            float vv = fmaxf(acc[mt][nt][r], 0.f);
            C[((size_t)(g * 4 + ti) * 30 + t) * 416 + f] = __float2bfloat16(vv);
          }
        }
      }
    }
  }
}

// ---------------------------------------------------------------------------
// K_ATTN: score[r] = sum_a tanh( (C[r,:] @ v[:,a]) + vb[a] ) * q[a]
// ---------------------------------------------------------------------------
__global__ __launch_bounds__(512) void k_attn(
    const __hip_bfloat16* __restrict__ C, const __hip_bfloat16* __restrict__ vT,
    const float* __restrict__ vbp, const float* __restrict__ qp,
    float* __restrict__ score)
{
  __shared__ __align__(16) ushort Clds[256 * 40];
  __shared__ __align__(16) ushort Vlds[224 * 40];
  __shared__ float sred[2][256];
  const int tid = threadIdx.x;
  const int lane = tid & 63, wid = tid >> 6;
  const int wm = wid >> 1, wn = wid & 1;
  const int l15 = lane & 15, l4 = lane >> 4;
  const size_t row0 = (size_t)blockIdx.x * 256;

  f32x4 acc[4][7];
  float ql[7];
#pragma unroll
  for (int nt = 0; nt < 7; ++nt) {
    int a = wn * 112 + nt * 16 + l15;
    ql[nt] = qp[a];
    float vbv = vbp[a];
#pragma unroll
    for (int mt = 0; mt < 4; ++mt) {
      acc[mt][nt][0] = vbv; acc[mt][nt][1] = vbv;
      acc[mt][nt][2] = vbv; acc[mt][nt][3] = vbv;
    }
  }

  for (int ks = 0; ks < 13; ++ks) {
    for (int idx = tid; idx < 1024; idx += 512) {
      int r = idx >> 2, c = idx & 3;
      *(uint4*)(&Clds[r * 40 + c * 8]) =
          *(const uint4*)((const ushort*)C + (row0 + r) * 416 + ks * 32 + c * 8);
    }
    for (int idx = tid; idx < 896; idx += 512) {
      int a = idx >> 2, c = idx & 3;
      *(uint4*)(&Vlds[a * 40 + c * 8]) =
          *(const uint4*)((const ushort*)vT + a * 416 + ks * 32 + c * 8);
    }
    __syncthreads();
    bf16x8 cf[4];
#pragma unroll
    for (int mt = 0; mt < 4; ++mt)
      cf[mt] = *(const bf16x8*)(&Clds[(wm * 64 + mt * 16 + l15) * 40 + l4 * 8]);
#pragma unroll
    for (int nt = 0; nt < 7; ++nt) {
      bf16x8 vf = *(const bf16x8*)(&Vlds[(wn * 112 + nt * 16 + l15) * 40 + l4 * 8]);
#pragma unroll
      for (int mt = 0; mt < 4; ++mt)
        acc[mt][nt] = __builtin_amdgcn_mfma_f32_16x16x32_bf16(cf[mt], vf, acc[mt][nt], 0, 0, 0);
    }
    __syncthreads();
  }

  float sums[4][4];
#pragma unroll
  for (int mt = 0; mt < 4; ++mt)
#pragma unroll
    for (int r = 0; r < 4; ++r) sums[mt][r] = 0.f;
#pragma unroll
  for (int mt = 0; mt < 4; ++mt)
#pragma unroll
    for (int nt = 0; nt < 7; ++nt)
#pragma unroll
      for (int r = 0; r < 4; ++r)
        sums[mt][r] += tanhf(acc[mt][nt][r]) * ql[nt];
#pragma unroll
  for (int mask = 1; mask < 16; mask <<= 1)
#pragma unroll
    for (int mt = 0; mt < 4; ++mt)
#pragma unroll
      for (int r = 0; r < 4; ++r)
        sums[mt][r] += __shfl_xor(sums[mt][r], mask);

  float outv = 0.f;
#pragma unroll
  for (int mt = 0; mt < 4; ++mt)
#pragma unroll
    for (int r = 0; r < 4; ++r)
      if (l15 == mt * 4 + r) outv = sums[mt][r];
  sred[wn][wm * 64 + (l15 >> 2) * 16 + l4 * 4 + (l15 & 3)] = outv;
  __syncthreads();
  if (tid < 256) score[row0 + tid] = sred[0][tid] + sred[1][tid];
}

// ---------------------------------------------------------------------------
// K2: softmax over the N (titles) axis, per (b,t).
// ---------------------------------------------------------------------------
__global__ void k2_softmax_n(const float* __restrict__ score, float* __restrict__ alpha) {
  int i = blockIdx.x * 256 + threadIdx.x;
  if (i >= BB * TT) return;
  int b = i / TT, t = i - b * TT;
  int base = b * (NN * TT) + t;
  float m = -1e30f;
  for (int n = 0; n < NN; ++n) m = fmaxf(m, score[base + n * TT]);
  float s = 0.f;
  for (int n = 0; n < NN; ++n) s += __expf(score[base + n * TT] - m);
  float inv = 1.f / s;
  for (int n = 0; n < NN; ++n)
    alpha[base + n * TT] = __expf(score[base + n * TT] - m) * inv;
}

// ---------------------------------------------------------------------------
// K3: e[bn,f] = sum_t alpha[bn,t] * C[bn,t,f]  -> bf16 [3200][416] padded
// ---------------------------------------------------------------------------
__global__ __launch_bounds__(256) void k3_wsum(
    const float* __restrict__ alpha, const __hip_bfloat16* __restrict__ C,
    __hip_bfloat16* __restrict__ Ebf) {
  __shared__ float al[TT];
  const int bn = blockIdx.x;
  const int tid = threadIdx.x;
  if (tid < TT) al[tid] = alpha[bn * TT + tid];
  __syncthreads();
  for (int f = tid; f < 416; f += 256) {
    float s = 0.f;
    if (f < FN) {
#pragma unroll
      for (int t = 0; t < TT; ++t)
        s = fmaf(al[t], __bfloat162float(C[((size_t)bn * TT + t) * 416 + f]), s);
    }
    Ebf[(size_t)bn * 416 + f] = __float2bfloat16(s);
  }
}

// ---------------------------------------------------------------------------
// K4: gx = e @ W_ih^T + b_ih via bf16 MFMA. M=3200, N=1344(pad), K=416.
// ---------------------------------------------------------------------------
__global__ __launch_bounds__(512) void k4_gx_mfma(
    const __hip_bfloat16* __restrict__ Ebf,   // [3200][416]
    const __hip_bfloat16* __restrict__ Wih,   // [1344][416]
    const float* __restrict__ b_ih,           // [1200]
    float* __restrict__ gx)                   // [3200][1200]
{
  __shared__ __align__(16) ushort Alds[128 * 40];
  __shared__ __align__(16) ushort Blds[448 * 40];
  const int tid = threadIdx.x;
  const int lane = tid & 63, wid = tid >> 6;
  const int wm = wid >> 2, wn = wid & 3;
  const int l15 = lane & 15, l4 = lane >> 4;
  const int mb = blockIdx.x / 3;
  const int nb = blockIdx.x - mb * 3;
  const int row0 = mb * 128;
  const int n0 = nb * 448;

  f32x4 acc[4][7];
#pragma unroll
  for (int nt = 0; nt < 7; ++nt) {
    int j = n0 + wn * 112 + nt * 16 + l15;
    float bj = (j < 1200) ? b_ih[j] : 0.f;
#pragma unroll
    for (int mt = 0; mt < 4; ++mt) {
      acc[mt][nt][0] = bj; acc[mt][nt][1] = bj;
      acc[mt][nt][2] = bj; acc[mt][nt][3] = bj;
    }
  }

  const int ar = tid >> 2, ac = tid & 3;
  for (int ks = 0; ks < 13; ++ks) {
    *(uint4*)(&Alds[ar * 40 + ac * 8]) =
        *(const uint4*)((const ushort*)Ebf + (size_t)(row0 + ar) * 416 + ks * 32 + ac * 8);
    for (int idx = tid; idx < 1792; idx += 512) {
      int r = idx >> 2, c = idx & 3;
      *(uint4*)(&Blds[r * 40 + c * 8]) =
          *(const uint4*)((const ushort*)Wih + (size_t)(n0 + r) * 416 + ks * 32 + c * 8);
    }
    __syncthreads();
    bf16x8 af[4];
#pragma unroll
    for (int mt = 0; mt < 4; ++mt)
      af[mt] = *(const bf16x8*)(&Alds[(wm * 64 + mt * 16 + l15) * 40 + l4 * 8]);
#pragma unroll
    for (int nt = 0; nt < 7; ++nt) {
      bf16x8 bfr = *(const bf16x8*)(&Blds[(wn * 112 + nt * 16 + l15) * 40 + l4 * 8]);
#pragma unroll
      for (int mt = 0; mt < 4; ++mt)
        acc[mt][nt] = __builtin_amdgcn_mfma_f32_16x16x32_bf16(af[mt], bfr, acc[mt][nt], 0, 0, 0);
    }
    __syncthreads();
  }

#pragma unroll
  for (int mt = 0; mt < 4; ++mt) {
    int row = row0 + wm * 64 + mt * 16 + l4 * 4;
#pragma unroll
    for (int nt = 0; nt < 7; ++nt) {
      int j = n0 + wn * 112 + nt * 16 + l15;
      if (j < 1200) {
#pragma unroll
        for (int r = 0; r < 4; ++r)
          gx[(size_t)(row + r) * 1200 + j] = acc[mt][nt][r];
      }
    }
  }
}

// ---------------------------------------------------------------------------
// GRU: 50-launch chain (grid.sync measured 7x slower on this chip — per-XCD
// L2 non-coherence makes device-scope fences cost ~35us/step at 256 blocks).
// ---------------------------------------------------------------------------
__global__ void k5_init(const int* __restrict__ user_id,
                        const float* __restrict__ user_emb,
                        float* __restrict__ h0) {
  int idx = blockIdx.x * 256 + threadIdx.x;
  if (idx < BB * GG) {
    int b = idx / GG, g = idx - b * GG;
    h0[idx] = user_emb[(long)user_id[b] * GG + g];
  }
}

__global__ __launch_bounds__(256) void k5_step(
    const float* __restrict__ h_prev, float* __restrict__ h_next,
    const float* __restrict__ Wpack, const float* __restrict__ b_hh,
    const float* __restrict__ gx, const int* __restrict__ hist_len, int step)
{
  const int gc = blockIdx.x & 7;
  const int bg = blockIdx.x >> 3;
  const int tid = threadIdx.x;
  __shared__ float hl[2][GG];
  __shared__ float ghl[2][3][50];

  for (int i = tid; i < 2 * GG; i += 256) {
    int b = i / GG, g = i - b * GG;
    hl[b][g] = h_prev[(2 * bg + b) * GG + g];
  }
  __syncthreads();

  if (tid < 150) {
    float acc0 = 0.f, acc1 = 0.f;
    const float* wp = Wpack + (size_t)gc * 400 * 150 + tid;
#pragma unroll 8
    for (int g = 0; g < GG; ++g) {
      float w = wp[g * 150];
      acc0 = fmaf(hl[0][g], w, acc0);
      acc1 = fmaf(hl[1][g], w, acc1);
    }
    int gate = tid / 50, gl = tid - gate * 50;
    float bb = b_hh[gate * 400 + gc * 50 + gl];
    ghl[0][gate][gl] = acc0 + bb;
    ghl[1][gate][gl] = acc1 + bb;
  }
  __syncthreads();

  if (tid < 100) {
    int b = tid / 50, gl = tid - (tid / 50) * 50;
    int babs = 2 * bg + b;
    int g = gc * 50 + gl;
    const float* gxp = gx + ((size_t)babs * NN + step) * 1200;
    float xr = gxp[g], xz = gxp[400 + g], xn = gxp[800 + g];
    float hr = ghl[b][0][gl], hz = ghl[b][1][gl], hn = ghl[b][2][gl];
    float r = 1.f / (1.f + __expf(-(xr + hr)));
    float z = 1.f / (1.f + __expf(-(xz + hz)));
    float nv = tanhf(xn + r * hn);
    float hold = hl[b][g];
    float hnew = (1.f - z) * nv + z * hold;
    h_next[babs * GG + g] = (step < hist_len[babs]) ? hnew : hold;
  }
}

__global__ void k5_out(const float* __restrict__ h, float* __restrict__ out) {
  int idx = blockIdx.x * 256 + threadIdx.x;
  if (idx < BB * GG) out[idx] = h[idx];
}

// ---------------------------------------------------------------------------
extern "C" void kernel_launch(void* const* d_in, const int* in_sizes, int n_in,
                              void* d_out, int out_size, void* d_ws, size_t ws_size,
                              hipStream_t stream) {
  const int*   user_id   = (const int*)d_in[0];
  const int*   title     = (const int*)d_in[1];
  const int*   hist_len  = (const int*)d_in[2];
  const float* word_emb  = (const float*)d_in[3];
  const float* conv_w    = (const float*)d_in[4];
  const float* conv_b    = (const float*)d_in[5];
  const float* v         = (const float*)d_in[6];
  const float* vb        = (const float*)d_in[7];
  const float* q         = (const float*)d_in[8];
  const float* user_emb  = (const float*)d_in[9];
  const float* W_ih      = (const float*)d_in[10];
  const float* W_hh      = (const float*)d_in[11];
  const float* b_ih      = (const float*)d_in[12];
  const float* b_hh      = (const float*)d_in[13];
  float* out = (float*)d_out;

  char* ws = (char*)d_ws;
  size_t off = 0;
  auto take = [&](size_t bytes) {
    char* p = ws + off;
    off = (off + bytes + 255) & ~(size_t)255;
    return p;
  };
  __hip_bfloat16* C      = (__hip_bfloat16*)take((size_t)BB * NN * TT * 416 * 2);  // 79.9MB
  float* score  = (float*)take((size_t)BB * NN * TT * 4);
  float* alpha  = (float*)take((size_t)BB * NN * TT * 4);
  __hip_bfloat16* Ebf    = (__hip_bfloat16*)take((size_t)BB * NN * 416 * 2);
  __hip_bfloat16* Wih_bf = (__hip_bfloat16*)take((size_t)1344 * 416 * 2);
  float* Wpack  = (float*)take((size_t)8 * 400 * 150 * 4);
  float* gx     = (float*)take((size_t)BB * NN * 1200 * 4);
  float* h0     = (float*)take((size_t)BB * GG * 4);
  float* h1     = (float*)take((size_t)BB * GG * 4);
  __hip_bfloat16* emb_bf = (__hip_bfloat16*)take((size_t)50000 * 320 * 2);        // 32MB
  __hip_bfloat16* WT     = (__hip_bfloat16*)take((size_t)448 * 960 * 2);
  __hip_bfloat16* vT     = (__hip_bfloat16*)take((size_t)224 * 416 * 2);
  float* qp     = (float*)take(224 * 4);
  float* vbp    = (float*)take(224 * 4);
  (void)ws_size;

  k_pack_whh<<<(8 * 400 * 150 + 255) / 256, 256, 0, stream>>>(W_hh, Wpack);
  k_prep_emb<<<(50000 * 320 + 255) / 256, 256, 0, stream>>>(word_emb, emb_bf);
  k_prep_wt<<<(448 * 960 + 255) / 256, 256, 0, stream>>>(conv_w, WT);
  k_prep_v<<<(224 * 416 + 255) / 256, 256, 0, stream>>>(v, vT);
  k_prep_qvb<<<1, 256, 0, stream>>>(q, vb, qp, vbp);
  k_prep_wih<<<(1344 * 416 + 255) / 256, 256, 0, stream>>>(W_ih, Wih_bf);

  k_conv<<<BB * NN / 4, 512, 0, stream>>>(title, emb_bf, WT, conv_b, C);
  k_attn<<<BB * NN * TT / 256, 512, 0, stream>>>(C, vT, vbp, qp, score);
  k2_softmax_n<<<(BB * TT + 255) / 256, 256, 0, stream>>>(score, alpha);
  k3_wsum<<<BB * NN, 256, 0, stream>>>(alpha, C, Ebf);
  k4_gx_mfma<<<75, 512, 0, stream>>>(Ebf, Wih_bf, b_ih, gx);

  k5_init<<<(BB * GG + 255) / 256, 256, 0, stream>>>(user_id, user_emb, h0);
  float* hbuf[2] = {h0, h1};
  for (int step = 0; step < NN; ++step) {
    k5_step<<<256, 256, 0, stream>>>(hbuf[step & 1], hbuf[(step + 1) & 1],
                                     Wpack, b_hh, gx, hist_len, step);
  }
  k5_out<<<(BB * GG + 255) / 256, 256, 0, stream>>>(h0, out);
}

// Round 8
// 961.526 us; speedup vs baseline: 1.0003x; 1.0003x over previous
//
#include <hip/hip_runtime.h>
#include <hip/hip_bf16.h>

#define BB 64
#define NN 50
#define TT 30
#define EE 300
#define FN 400
#define AA 200
#define GG 400

typedef __attribute__((ext_vector_type(8))) short bf16x8;
typedef __attribute__((ext_vector_type(4))) float f32x4;

// ---------------------------------------------------------------------------
// Prep kernels (one-time, tiny)
// ---------------------------------------------------------------------------
__global__ void k_pack_whh(const float* __restrict__ Whh, float* __restrict__ Wpack) {
  int idx = blockIdx.x * 256 + threadIdx.x;
  if (idx < 8 * 400 * 150) {
    int jl = idx % 150;
    int g = (idx / 150) % 400;
    int gc = idx / (150 * 400);
    int gate = jl / 50, gl = jl - gate * 50;
    int j = gate * 400 + gc * 50 + gl;
    Wpack[idx] = Whh[j * 400 + g];
  }
}

// word_emb fp32 [50000][300] -> bf16 [50000][320] (zero pad cols 300..319)
__global__ void k_prep_emb(const float* __restrict__ w, __hip_bfloat16* __restrict__ o) {
  long i = (long)blockIdx.x * 256 + threadIdx.x;
  if (i < (long)50000 * 320) {
    int row = (int)(i / 320), c = (int)(i % 320);
    o[i] = __float2bfloat16(c < EE ? w[(long)row * EE + c] : 0.f);
  }
}

// conv_w fp32 [3][300][400] (k,e,f) -> WT bf16 [448 f][960 k] (zero padded)
__global__ void k_prep_wt(const float* __restrict__ cw, __hip_bfloat16* __restrict__ o) {
  int i = blockIdx.x * 256 + threadIdx.x;
  if (i < 448 * 960) {
    int f = i / 960, kk = i % 960;
    int ko = kk / 320, e = kk % 320;
    float val = (f < FN && e < EE) ? cw[(ko * EE + e) * FN + f] : 0.f;
    o[i] = __float2bfloat16(val);
  }
}

// v fp32 [400 f][200 a] -> vT bf16 [224 a][416 f] (zero padded)
__global__ void k_prep_v(const float* __restrict__ v, __hip_bfloat16* __restrict__ o) {
  int i = blockIdx.x * 256 + threadIdx.x;
  if (i < 224 * 416) {
    int a = i / 416, f = i % 416;
    o[i] = __float2bfloat16((a < AA && f < FN) ? v[f * AA + a] : 0.f);
  }
}

__global__ void k_prep_qvb(const float* __restrict__ q, const float* __restrict__ vb,
                           float* __restrict__ qp, float* __restrict__ vbp) {
  int i = threadIdx.x;
  if (i < 224) {
    qp[i]  = i < AA ? q[i]  : 0.f;
    vbp[i] = i < AA ? vb[i] : 0.f;
  }
}

// W_ih fp32 [1200 j][400 f] -> bf16 [1344 j][416 f] zero-padded
__global__ void k_prep_wih(const float* __restrict__ w, __hip_bfloat16* __restrict__ o) {
  int i = blockIdx.x * 256 + threadIdx.x;
  if (i < 1344 * 416) {
    int j = i / 416, f = i % 416;
    o[i] = __float2bfloat16((j < 1200 && f < 400) ? w[j * 400 + f] : 0.f);
  }
}

// ---------------------------------------------------------------------------
// K_CONV: bf16 MFMA implicit-GEMM conv1d(K=3,pad=1) + bias + ReLU.
// ---------------------------------------------------------------------------
__global__ __launch_bounds__(512) void k_conv(
    const int* __restrict__ title, const __hip_bfloat16* __restrict__ emb,
    const __hip_bfloat16* __restrict__ WT, const float* __restrict__ conv_b,
    __hip_bfloat16* __restrict__ C)
{
  __shared__ __align__(16) ushort Alds[128 * 40];
  __shared__ __align__(16) ushort Blds[448 * 40];
  __shared__ int words[120];
  const int g = blockIdx.x;
  const int tid = threadIdx.x;
  const int lane = tid & 63;
  const int wid = tid >> 6;
  const int wm = wid >> 2;
  const int wn = wid & 3;
  const int l15 = lane & 15;
  const int l4 = lane >> 4;

  if (tid < 120) words[tid] = title[g * 120 + tid];

  f32x4 acc[4][7];
  {
    float bias[7];
#pragma unroll
    for (int nt = 0; nt < 7; ++nt) {
      int f = wn * 112 + nt * 16 + l15;
      bias[nt] = (f < FN) ? conv_b[f] : 0.f;
    }
#pragma unroll
    for (int mt = 0; mt < 4; ++mt)
#pragma unroll
      for (int nt = 0; nt < 7; ++nt) {
        acc[mt][nt][0] = bias[nt]; acc[mt][nt][1] = bias[nt];
        acc[mt][nt][2] = bias[nt]; acc[mt][nt][3] = bias[nt];
      }
  }
  __syncthreads();

  const int ar = tid >> 2, ac = tid & 3;
  const int ati = ar >> 5, at = ar & 31;

  for (int ko = 0; ko < 3; ++ko) {
    int w = at + ko - 1;
    const bool valid = (w >= 0 && w < TT);
    const ushort* asrc = valid ? (const ushort*)emb + (size_t)words[ati * 30 + w] * 320
                               : (const ushort*)emb;
    for (int ks = 0; ks < 10; ++ks) {
      uint4 av = make_uint4(0u, 0u, 0u, 0u);
      if (valid) av = *(const uint4*)(asrc + ks * 32 + ac * 8);
      *(uint4*)(&Alds[ar * 40 + ac * 8]) = av;
      for (int idx = tid; idx < 1792; idx += 512) {
        int f = idx >> 2, c = idx & 3;
        *(uint4*)(&Blds[f * 40 + c * 8]) =
            *(const uint4*)((const ushort*)WT + f * 960 + ko * 320 + ks * 32 + c * 8);
      }
      __syncthreads();
      bf16x8 af[4];
#pragma unroll
      for (int mt = 0; mt < 4; ++mt)
        af[mt] = *(const bf16x8*)(&Alds[(wm * 64 + mt * 16 + l15) * 40 + l4 * 8]);
#pragma unroll
      for (int nt = 0; nt < 7; ++nt) {
        bf16x8 bfr = *(const bf16x8*)(&Blds[(wn * 112 + nt * 16 + l15) * 40 + l4 * 8]);
#pragma unroll
        for (int mt = 0; mt < 4; ++mt)
          acc[mt][nt] = __builtin_amdgcn_mfma_f32_16x16x32_bf16(af[mt], bfr, acc[mt][nt], 0, 0, 0);
      }
      __syncthreads();
    }
  }

#pragma unroll
  for (int mt = 0; mt < 4; ++mt) {
    int rowb = wm * 64 + mt * 16 + l4 * 4;
    int ti = rowb >> 5;
    int tb = rowb & 31;
#pragma unroll
    for (int nt = 0; nt < 7; ++nt) {
      int f = wn * 112 + nt * 16 + l15;
      if (f < 416) {
#pragma unroll
        for (int r = 0; r < 4; ++r) {
          int t = tb + r;
          if (t < TT) {
            float vv = fmaxf(acc[mt][nt][r], 0.f);
            C[((size_t)(g * 4 + ti) * 30 + t) * 416 + f] = __float2bfloat16(vv);
          }
        }
      }
    }
  }
}

// ---------------------------------------------------------------------------
// K_ATTN: score[r] = sum_a tanh( (C[r,:] @ v[:,a]) + vb[a] ) * q[a]
// ---------------------------------------------------------------------------
__global__ __launch_bounds__(512) void k_attn(
    const __hip_bfloat16* __restrict__ C, const __hip_bfloat16* __restrict__ vT,
    const float* __restrict__ vbp, const float* __restrict__ qp,
    float* __restrict__ score)
{
  __shared__ __align__(16) ushort Clds[256 * 40];
  __shared__ __align__(16) ushort Vlds[224 * 40];
  __shared__ float sred[2][256];
  const int tid = threadIdx.x;
  const int lane = tid & 63, wid = tid >> 6;
  const int wm = wid >> 1, wn = wid & 1;
  const int l15 = lane & 15, l4 = lane >> 4;
  const size_t row0 = (size_t)blockIdx.x * 256;

  f32x4 acc[4][7];
  float ql[7];
#pragma unroll
  for (int nt = 0; nt < 7; ++nt) {
    int a = wn * 112 + nt * 16 + l15;
    ql[nt] = qp[a];
    float vbv = vbp[a];
#pragma unroll
    for (int mt = 0; mt < 4; ++mt) {
      acc[mt][nt][0] = vbv; acc[mt][nt][1] = vbv;
      acc[mt][nt][2] = vbv; acc[mt][nt][3] = vbv;
    }
  }

  for (int ks = 0; ks < 13; ++ks) {
    for (int idx = tid; idx < 1024; idx += 512) {
      int r = idx >> 2, c = idx & 3;
      *(uint4*)(&Clds[r * 40 + c * 8]) =
          *(const uint4*)((const ushort*)C + (row0 + r) * 416 + ks * 32 + c * 8);
    }
    for (int idx = tid; idx < 896; idx += 512) {
      int a = idx >> 2, c = idx & 3;
      *(uint4*)(&Vlds[a * 40 + c * 8]) =
          *(const uint4*)((const ushort*)vT + a * 416 + ks * 32 + c * 8);
    }
    __syncthreads();
    bf16x8 cf[4];
#pragma unroll
    for (int mt = 0; mt < 4; ++mt)
      cf[mt] = *(const bf16x8*)(&Clds[(wm * 64 + mt * 16 + l15) * 40 + l4 * 8]);
#pragma unroll
    for (int nt = 0; nt < 7; ++nt) {
      bf16x8 vf = *(const bf16x8*)(&Vlds[(wn * 112 + nt * 16 + l15) * 40 + l4 * 8]);
#pragma unroll
      for (int mt = 0; mt < 4; ++mt)
        acc[mt][nt] = __builtin_amdgcn_mfma_f32_16x16x32_bf16(cf[mt], vf, acc[mt][nt], 0, 0, 0);
    }
    __syncthreads();
  }

  float sums[4][4];
#pragma unroll
  for (int mt = 0; mt < 4; ++mt)
#pragma unroll
    for (int r = 0; r < 4; ++r) sums[mt][r] = 0.f;
#pragma unroll
  for (int mt = 0; mt < 4; ++mt)
#pragma unroll
    for (int nt = 0; nt < 7; ++nt)
#pragma unroll
      for (int r = 0; r < 4; ++r)
        sums[mt][r] += tanhf(acc[mt][nt][r]) * ql[nt];
#pragma unroll
  for (int mask = 1; mask < 16; mask <<= 1)
#pragma unroll
    for (int mt = 0; mt < 4; ++mt)
#pragma unroll
      for (int r = 0; r < 4; ++r)
        sums[mt][r] += __shfl_xor(sums[mt][r], mask);

  float outv = 0.f;
#pragma unroll
  for (int mt = 0; mt < 4; ++mt)
#pragma unroll
    for (int r = 0; r < 4; ++r)
      if (l15 == mt * 4 + r) outv = sums[mt][r];
  sred[wn][wm * 64 + (l15 >> 2) * 16 + l4 * 4 + (l15 & 3)] = outv;
  __syncthreads();
  if (tid < 256) score[row0 + tid] = sred[0][tid] + sred[1][tid];
}

// ---------------------------------------------------------------------------
// K2: softmax over the N (titles) axis, per (b,t).
// ---------------------------------------------------------------------------
__global__ void k2_softmax_n(const float* __restrict__ score, float* __restrict__ alpha) {
  int i = blockIdx.x * 256 + threadIdx.x;
  if (i >= BB * TT) return;
  int b = i / TT, t = i - b * TT;
  int base = b * (NN * TT) + t;
  float m = -1e30f;
  for (int n = 0; n < NN; ++n) m = fmaxf(m, score[base + n * TT]);
  float s = 0.f;
  for (int n = 0; n < NN; ++n) s += __expf(score[base + n * TT] - m);
  float inv = 1.f / s;
  for (int n = 0; n < NN; ++n)
    alpha[base + n * TT] = __expf(score[base + n * TT] - m) * inv;
}

// ---------------------------------------------------------------------------
// K3: e[bn,f] = sum_t alpha[bn,t] * C[bn,t,f]  -> bf16 [3200][416] padded
// ---------------------------------------------------------------------------
__global__ __launch_bounds__(256) void k3_wsum(
    const float* __restrict__ alpha, const __hip_bfloat16* __restrict__ C,
    __hip_bfloat16* __restrict__ Ebf) {
  __shared__ float al[TT];
  const int bn = blockIdx.x;
  const int tid = threadIdx.x;
  if (tid < TT) al[tid] = alpha[bn * TT + tid];
  __syncthreads();
  for (int f = tid; f < 416; f += 256) {
    float s = 0.f;
    if (f < FN) {
#pragma unroll
      for (int t = 0; t < TT; ++t)
        s = fmaf(al[t], __bfloat162float(C[((size_t)bn * TT + t) * 416 + f]), s);
    }
    Ebf[(size_t)bn * 416 + f] = __float2bfloat16(s);
  }
}

// ---------------------------------------------------------------------------
// K4: gx = e @ W_ih^T + b_ih via bf16 MFMA. M=3200, N=1344(pad), K=416.
// ---------------------------------------------------------------------------
__global__ __launch_bounds__(512) void k4_gx_mfma(
    const __hip_bfloat16* __restrict__ Ebf,   // [3200][416]
    const __hip_bfloat16* __restrict__ Wih,   // [1344][416]
    const float* __restrict__ b_ih,           // [1200]
    float* __restrict__ gx)                   // [3200][1200]
{
  __shared__ __align__(16) ushort Alds[128 * 40];
  __shared__ __align__(16) ushort Blds[448 * 40];
  const int tid = threadIdx.x;
  const int lane = tid & 63, wid = tid >> 6;
  const int wm = wid >> 2, wn = wid & 3;
  const int l15 = lane & 15, l4 = lane >> 4;
  const int mb = blockIdx.x / 3;
  const int nb = blockIdx.x - mb * 3;
  const int row0 = mb * 128;
  const int n0 = nb * 448;

  f32x4 acc[4][7];
#pragma unroll
  for (int nt = 0; nt < 7; ++nt) {
    int j = n0 + wn * 112 + nt * 16 + l15;
    float bj = (j < 1200) ? b_ih[j] : 0.f;
#pragma unroll
    for (int mt = 0; mt < 4; ++mt) {
      acc[mt][nt][0] = bj; acc[mt][nt][1] = bj;
      acc[mt][nt][2] = bj; acc[mt][nt][3] = bj;
    }
  }

  const int ar = tid >> 2, ac = tid & 3;
  for (int ks = 0; ks < 13; ++ks) {
    *(uint4*)(&Alds[ar * 40 + ac * 8]) =
        *(const uint4*)((const ushort*)Ebf + (size_t)(row0 + ar) * 416 + ks * 32 + ac * 8);
    for (int idx = tid; idx < 1792; idx += 512) {
      int r = idx >> 2, c = idx & 3;
      *(uint4*)(&Blds[r * 40 + c * 8]) =
          *(const uint4*)((const ushort*)Wih + (size_t)(n0 + r) * 416 + ks * 32 + c * 8);
    }
    __syncthreads();
    bf16x8 af[4];
#pragma unroll
    for (int mt = 0; mt < 4; ++mt)
      af[mt] = *(const bf16x8*)(&Alds[(wm * 64 + mt * 16 + l15) * 40 + l4 * 8]);
#pragma unroll
    for (int nt = 0; nt < 7; ++nt) {
      bf16x8 bfr = *(const bf16x8*)(&Blds[(wn * 112 + nt * 16 + l15) * 40 + l4 * 8]);
#pragma unroll
      for (int mt = 0; mt < 4; ++mt)
        acc[mt][nt] = __builtin_amdgcn_mfma_f32_16x16x32_bf16(af[mt], bfr, acc[mt][nt], 0, 0, 0);
    }
    __syncthreads();
  }

#pragma unroll
  for (int mt = 0; mt < 4; ++mt) {
    int row = row0 + wm * 64 + mt * 16 + l4 * 4;
#pragma unroll
    for (int nt = 0; nt < 7; ++nt) {
      int j = n0 + wn * 112 + nt * 16 + l15;
      if (j < 1200) {
#pragma unroll
        for (int r = 0; r < 4; ++r)
          gx[(size_t)(row + r) * 1200 + j] = acc[mt][nt][r];
      }
    }
  }
}

// ---------------------------------------------------------------------------
// GRU: 50-launch chain (grid.sync measured 7x slower on this chip — per-XCD
// L2 non-coherence makes device-scope fences cost ~35us/step at 256 blocks).
// ---------------------------------------------------------------------------
__global__ void k5_init(const int* __restrict__ user_id,
                        const float* __restrict__ user_emb,
                        float* __restrict__ h0) {
  int idx = blockIdx.x * 256 + threadIdx.x;
  if (idx < BB * GG) {
    int b = idx / GG, g = idx - b * GG;
    h0[idx] = user_emb[(long)user_id[b] * GG + g];
  }
}

__global__ __launch_bounds__(256) void k5_step(
    const float* __restrict__ h_prev, float* __restrict__ h_next,
    const float* __restrict__ Wpack, const float* __restrict__ b_hh,
    const float* __restrict__ gx, const int* __restrict__ hist_len, int step)
{
  const int gc = blockIdx.x & 7;
  const int bg = blockIdx.x >> 3;
  const int tid = threadIdx.x;
  __shared__ float hl[2][GG];
  __shared__ float ghl[2][3][50];

  for (int i = tid; i < 2 * GG; i += 256) {
    int b = i / GG, g = i - b * GG;
    hl[b][g] = h_prev[(2 * bg + b) * GG + g];
  }
  __syncthreads();

  if (tid < 150) {
    float acc0 = 0.f, acc1 = 0.f;
    const float* wp = Wpack + (size_t)gc * 400 * 150 + tid;
#pragma unroll 8
    for (int g = 0; g < GG; ++g) {
      float w = wp[g * 150];
      acc0 = fmaf(hl[0][g], w, acc0);
      acc1 = fmaf(hl[1][g], w, acc1);
    }
    int gate = tid / 50, gl = tid - gate * 50;
    float bb = b_hh[gate * 400 + gc * 50 + gl];
    ghl[0][gate][gl] = acc0 + bb;
    ghl[1][gate][gl] = acc1 + bb;
  }
  __syncthreads();

  if (tid < 100) {
    int b = tid / 50, gl = tid - (tid / 50) * 50;
    int babs = 2 * bg + b;
    int g = gc * 50 + gl;
    const float* gxp = gx + ((size_t)babs * NN + step) * 1200;
    float xr = gxp[g], xz = gxp[400 + g], xn = gxp[800 + g];
    float hr = ghl[b][0][gl], hz = ghl[b][1][gl], hn = ghl[b][2][gl];
    float r = 1.f / (1.f + __expf(-(xr + hr)));
    float z = 1.f / (1.f + __expf(-(xz + hz)));
    float nv = tanhf(xn + r * hn);
    float hold = hl[b][g];
    float hnew = (1.f - z) * nv + z * hold;
    h_next[babs * GG + g] = (step < hist_len[babs]) ? hnew : hold;
  }
}

__global__ void k5_out(const float* __restrict__ h, float* __restrict__ out) {
  int idx = blockIdx.x * 256 + threadIdx.x;
  if (idx < BB * GG) out[idx] = h[idx];
}

// ---------------------------------------------------------------------------
extern "C" void kernel_launch(void* const* d_in, const int* in_sizes, int n_in,
                              void* d_out, int out_size, void* d_ws, size_t ws_size,
                              hipStream_t stream) {
  const int*   user_id   = (const int*)d_in[0];
  const int*   title     = (const int*)d_in[1];
  const int*   hist_len  = (const int*)d_in[2];
  const float* word_emb  = (const float*)d_in[3];
  const float* conv_w    = (const float*)d_in[4];
  const float* conv_b    = (const float*)d_in[5];
  const float* v         = (const float*)d_in[6];
  const float* vb        = (const float*)d_in[7];
  const float* q         = (const float*)d_in[8];
  const float* user_emb  = (const float*)d_in[9];
  const float* W_ih      = (const float*)d_in[10];
  const float* W_hh      = (const float*)d_in[11];
  const float* b_ih      = (const float*)d_in[12];
  const float* b_hh      = (const float*)d_in[13];
  float* out = (float*)d_out;

  char* ws = (char*)d_ws;
  size_t off = 0;
  auto take = [&](size_t bytes) {
    char* p = ws + off;
    off = (off + bytes + 255) & ~(size_t)255;
    return p;
  };
  __hip_bfloat16* C      = (__hip_bfloat16*)take((size_t)BB * NN * TT * 416 * 2);  // 79.9MB
  float* score  = (float*)take((size_t)BB * NN * TT * 4);
  float* alpha  = (float*)take((size_t)BB * NN * TT * 4);
  __hip_bfloat16* Ebf    = (__hip_bfloat16*)take((size_t)BB * NN * 416 * 2);
  __hip_bfloat16* Wih_bf = (__hip_bfloat16*)take((size_t)1344 * 416 * 2);
  float* Wpack  = (float*)take((size_t)8 * 400 * 150 * 4);
  float* gx     = (float*)take((size_t)BB * NN * 1200 * 4);
  float* h0     = (float*)take((size_t)BB * GG * 4);
  float* h1     = (float*)take((size_t)BB * GG * 4);
  __hip_bfloat16* emb_bf = (__hip_bfloat16*)take((size_t)50000 * 320 * 2);        // 32MB
  __hip_bfloat16* WT     = (__hip_bfloat16*)take((size_t)448 * 960 * 2);
  __hip_bfloat16* vT     = (__hip_bfloat16*)take((size_t)224 * 416 * 2);
  float* qp     = (float*)take(224 * 4);
  float* vbp    = (float*)take(224 * 4);
  (void)ws_size;

  k_pack_whh<<<(8 * 400 * 150 + 255) / 256, 256, 0, stream>>>(W_hh, Wpack);
  k_prep_emb<<<(50000 * 320 + 255) / 256, 256, 0, stream>>>(word_emb, emb_bf);
  k_prep_wt<<<(448 * 960 + 255) / 256, 256, 0, stream>>>(conv_w, WT);
  k_prep_v<<<(224 * 416 + 255) / 256, 256, 0, stream>>>(v, vT);
  k_prep_qvb<<<1, 256, 0, stream>>>(q, vb, qp, vbp);
  k_prep_wih<<<(1344 * 416 + 255) / 256, 256, 0, stream>>>(W_ih, Wih_bf);

  k_conv<<<BB * NN / 4, 512, 0, stream>>>(title, emb_bf, WT, conv_b, C);
  k_attn<<<BB * NN * TT / 256, 512, 0, stream>>>(C, vT, vbp, qp, score);
  k2_softmax_n<<<(BB * TT + 255) / 256, 256, 0, stream>>>(score, alpha);
  k3_wsum<<<BB * NN, 256, 0, stream>>>(alpha, C, Ebf);
  k4_gx_mfma<<<75, 512, 0, stream>>>(Ebf, Wih_bf, b_ih, gx);

  k5_init<<<(BB * GG + 255) / 256, 256, 0, stream>>>(user_id, user_emb, h0);
  float* hbuf[2] = {h0, h1};
  for (int step = 0; step < NN; ++step) {
    k5_step<<<256, 256, 0, stream>>>(hbuf[step & 1], hbuf[(step + 1) & 1],
                                     Wpack, b_hh, gx, hist_len, step);
  }
  k5_out<<<(BB * GG + 255) / 256, 256, 0, stream>>>(h0, out);
}

// Round 9
// 889.856 us; speedup vs baseline: 1.0809x; 1.0805x over previous
//
#include <hip/hip_runtime.h>
#include <hip/hip_bf16.h>

#define BB 64
#define NN 50
#define TT 30
#define EE 300
#define FN 400
#define AA 200
#define GG 400

typedef __attribute__((ext_vector_type(8))) short bf16x8;
typedef __attribute__((ext_vector_type(4))) float f32x4;

// ---------------------------------------------------------------------------
// Prep kernels (one-time, tiny)
// ---------------------------------------------------------------------------
__global__ void k_pack_whh(const float* __restrict__ Whh, float* __restrict__ Wpack) {
  int idx = blockIdx.x * 256 + threadIdx.x;
  if (idx < 8 * 400 * 150) {
    int jl = idx % 150;
    int g = (idx / 150) % 400;
    int gc = idx / (150 * 400);
    int gate = jl / 50, gl = jl - gate * 50;
    int j = gate * 400 + gc * 50 + gl;
    Wpack[idx] = Whh[j * 400 + g];
  }
}

// word_emb fp32 [50000][300] -> bf16 [50000][320] (zero pad cols 300..319)
__global__ void k_prep_emb(const float* __restrict__ w, __hip_bfloat16* __restrict__ o) {
  long i = (long)blockIdx.x * 256 + threadIdx.x;
  if (i < (long)50000 * 320) {
    int row = (int)(i / 320), c = (int)(i % 320);
    o[i] = __float2bfloat16(c < EE ? w[(long)row * EE + c] : 0.f);
  }
}

// conv_w fp32 [3][300][400] (k,e,f) -> WT2 bf16 [30 s][448 f][32 kk]:
// WT2[s][f][kk] = conv_w[s/10][(s%10)*32+kk][f] (zero-padded)
__global__ void k_prep_wt2(const float* __restrict__ cw, __hip_bfloat16* __restrict__ o) {
  int i = blockIdx.x * 256 + threadIdx.x;
  if (i < 30 * 448 * 32) {
    int kk = i & 31, f = (i >> 5) % 448, s = i / (448 * 32);
    int ko = s / 10, e = (s - ko * 10) * 32 + kk;
    float val = (f < FN && e < EE) ? cw[(ko * EE + e) * FN + f] : 0.f;
    o[i] = __float2bfloat16(val);
  }
}

// v fp32 [400 f][200 a] -> vT bf16 [224 a][416 f] (zero padded)
__global__ void k_prep_v(const float* __restrict__ v, __hip_bfloat16* __restrict__ o) {
  int i = blockIdx.x * 256 + threadIdx.x;
  if (i < 224 * 416) {
    int a = i / 416, f = i % 416;
    o[i] = __float2bfloat16((a < AA && f < FN) ? v[f * AA + a] : 0.f);
  }
}

__global__ void k_prep_qvb(const float* __restrict__ q, const float* __restrict__ vb,
                           float* __restrict__ qp, float* __restrict__ vbp) {
  int i = threadIdx.x;
  if (i < 224) {
    qp[i]  = i < AA ? q[i]  : 0.f;
    vbp[i] = i < AA ? vb[i] : 0.f;
  }
}

// W_ih fp32 [1200 j][400 f] -> bf16 [1344 j][416 f] zero-padded
__global__ void k_prep_wih(const float* __restrict__ w, __hip_bfloat16* __restrict__ o) {
  int i = blockIdx.x * 256 + threadIdx.x;
  if (i < 1344 * 416) {
    int j = i / 416, f = i % 416;
    o[i] = __float2bfloat16((j < 1200 && f < 400) ? w[j * 400 + f] : 0.f);
  }
}

// ---------------------------------------------------------------------------
// K_CONV v2: barrier-free MFMA conv.
// Block = 2 titles, 256 thr (4 waves, wn = wid covers f cols wn*112..+112).
// Emb tile resident in LDS once: E[2 ti][34 slot][328] (slot = word+1; slots
// 0,31,32,33 zero). A-fragment for (ko,ks) = ds_read at slot t+ko — no
// restaging, no K-loop barriers. B fragments read directly from L2-resident
// WT2[30][448][32] (perfectly coalesced; 860KB, L2-hot across 1600 blocks).
// ---------------------------------------------------------------------------
__global__ __launch_bounds__(256) void k_conv(
    const int* __restrict__ title, const __hip_bfloat16* __restrict__ emb,
    const __hip_bfloat16* __restrict__ WT2, const float* __restrict__ conv_b,
    __hip_bfloat16* __restrict__ C)
{
  __shared__ __align__(16) ushort E[2][34][328];
  __shared__ int words[60];
  const int g = blockIdx.x;       // titles 2g, 2g+1
  const int tid = threadIdx.x;
  const int lane = tid & 63, wn = tid >> 6;
  const int l15 = lane & 15, l4 = lane >> 4;

  if (tid < 60) words[tid] = title[g * 60 + tid];
  __syncthreads();

  // stage 60 emb rows (coalesced 640B each) into slots 1..30
  for (int idx = tid; idx < 2400; idx += 256) {
    int row = idx / 40, c = idx - row * 40;
    int ti = row / 30, w = row - ti * 30;
    const ushort* src = (const ushort*)emb + (size_t)words[row] * 320 + c * 8;
    *(uint4*)(&E[ti][w + 1][c * 8]) = *(const uint4*)src;
  }
  // zero slots 0,31,32,33 (conv padding + ko-shift overflow)
  for (int idx = tid; idx < 320; idx += 256) {
    int z = idx / 40, c = idx - z * 40;
    int ti = z >> 2, sl = z & 3;
    int slot = (sl == 0) ? 0 : 30 + sl;
    *(uint4*)(&E[ti][slot][c * 8]) = make_uint4(0u, 0u, 0u, 0u);
  }
  __syncthreads();

  f32x4 acc[4][7];
#pragma unroll
  for (int nt = 0; nt < 7; ++nt) {
    int f = wn * 112 + nt * 16 + l15;
    float bj = (f < FN) ? conv_b[f] : 0.f;
#pragma unroll
    for (int mt = 0; mt < 4; ++mt) {
      acc[mt][nt][0] = bj; acc[mt][nt][1] = bj;
      acc[mt][nt][2] = bj; acc[mt][nt][3] = bj;
    }
  }

  const ushort* Bbase = (const ushort*)WT2 + (size_t)(wn * 112 + l15) * 32 + l4 * 8;

#pragma unroll
  for (int ko = 0; ko < 3; ++ko) {
#pragma unroll
    for (int ks = 0; ks < 10; ++ks) {
      const int s = ko * 10 + ks;
      bf16x8 bq[7];
#pragma unroll
      for (int nt = 0; nt < 7; ++nt)
        bq[nt] = *(const bf16x8*)(Bbase + (size_t)s * 14336 + nt * 512);
      bf16x8 af[4];
#pragma unroll
      for (int mt = 0; mt < 4; ++mt) {
        int row = mt * 16 + l15;
        int ti = row >> 5, slot = (row & 31) + ko;
        af[mt] = *(const bf16x8*)(&E[ti][slot][ks * 32 + l4 * 8]);
      }
#pragma unroll
      for (int nt = 0; nt < 7; ++nt)
#pragma unroll
        for (int mt = 0; mt < 4; ++mt)
          acc[mt][nt] = __builtin_amdgcn_mfma_f32_16x16x32_bf16(af[mt], bq[nt], acc[mt][nt], 0, 0, 0);
    }
  }

  // epilogue: ReLU + store C [3200*30][416] bf16
#pragma unroll
  for (int mt = 0; mt < 4; ++mt) {
    int rowb = mt * 16 + l4 * 4;
#pragma unroll
    for (int nt = 0; nt < 7; ++nt) {
      int f = wn * 112 + nt * 16 + l15;
      if (f < 416) {
#pragma unroll
        for (int r = 0; r < 4; ++r) {
          int row = rowb + r;
          int ti = row >> 5, t = row & 31;
          if (t < TT) {
            float vv = fmaxf(acc[mt][nt][r], 0.f);
            C[((size_t)(g * 2 + ti) * 30 + t) * 416 + f] = __float2bfloat16(vv);
          }
        }
      }
    }
  }
}

// ---------------------------------------------------------------------------
// K_ATTN: score[r] = sum_a tanh( (C[r,:] @ v[:,a]) + vb[a] ) * q[a]
// ---------------------------------------------------------------------------
__global__ __launch_bounds__(512) void k_attn(
    const __hip_bfloat16* __restrict__ C, const __hip_bfloat16* __restrict__ vT,
    const float* __restrict__ vbp, const float* __restrict__ qp,
    float* __restrict__ score)
{
  __shared__ __align__(16) ushort Clds[256 * 40];
  __shared__ __align__(16) ushort Vlds[224 * 40];
  __shared__ float sred[2][256];
  const int tid = threadIdx.x;
  const int lane = tid & 63, wid = tid >> 6;
  const int wm = wid >> 1, wn = wid & 1;
  const int l15 = lane & 15, l4 = lane >> 4;
  const size_t row0 = (size_t)blockIdx.x * 256;

  f32x4 acc[4][7];
  float ql[7];
#pragma unroll
  for (int nt = 0; nt < 7; ++nt) {
    int a = wn * 112 + nt * 16 + l15;
    ql[nt] = qp[a];
    float vbv = vbp[a];
#pragma unroll
    for (int mt = 0; mt < 4; ++mt) {
      acc[mt][nt][0] = vbv; acc[mt][nt][1] = vbv;
      acc[mt][nt][2] = vbv; acc[mt][nt][3] = vbv;
    }
  }

  for (int ks = 0; ks < 13; ++ks) {
    for (int idx = tid; idx < 1024; idx += 512) {
      int r = idx >> 2, c = idx & 3;
      *(uint4*)(&Clds[r * 40 + c * 8]) =
          *(const uint4*)((const ushort*)C + (row0 + r) * 416 + ks * 32 + c * 8);
    }
    for (int idx = tid; idx < 896; idx += 512) {
      int a = idx >> 2, c = idx & 3;
      *(uint4*)(&Vlds[a * 40 + c * 8]) =
          *(const uint4*)((const ushort*)vT + a * 416 + ks * 32 + c * 8);
    }
    __syncthreads();
    bf16x8 cf[4];
#pragma unroll
    for (int mt = 0; mt < 4; ++mt)
      cf[mt] = *(const bf16x8*)(&Clds[(wm * 64 + mt * 16 + l15) * 40 + l4 * 8]);
#pragma unroll
    for (int nt = 0; nt < 7; ++nt) {
      bf16x8 vf = *(const bf16x8*)(&Vlds[(wn * 112 + nt * 16 + l15) * 40 + l4 * 8]);
#pragma unroll
      for (int mt = 0; mt < 4; ++mt)
        acc[mt][nt] = __builtin_amdgcn_mfma_f32_16x16x32_bf16(cf[mt], vf, acc[mt][nt], 0, 0, 0);
    }
    __syncthreads();
  }

  float sums[4][4];
#pragma unroll
  for (int mt = 0; mt < 4; ++mt)
#pragma unroll
    for (int r = 0; r < 4; ++r) sums[mt][r] = 0.f;
#pragma unroll
  for (int mt = 0; mt < 4; ++mt)
#pragma unroll
    for (int nt = 0; nt < 7; ++nt)
#pragma unroll
      for (int r = 0; r < 4; ++r)
        sums[mt][r] += tanhf(acc[mt][nt][r]) * ql[nt];
#pragma unroll
  for (int mask = 1; mask < 16; mask <<= 1)
#pragma unroll
    for (int mt = 0; mt < 4; ++mt)
#pragma unroll
      for (int r = 0; r < 4; ++r)
        sums[mt][r] += __shfl_xor(sums[mt][r], mask);

  float outv = 0.f;
#pragma unroll
  for (int mt = 0; mt < 4; ++mt)
#pragma unroll
    for (int r = 0; r < 4; ++r)
      if (l15 == mt * 4 + r) outv = sums[mt][r];
  sred[wn][wm * 64 + (l15 >> 2) * 16 + l4 * 4 + (l15 & 3)] = outv;
  __syncthreads();
  if (tid < 256) score[row0 + tid] = sred[0][tid] + sred[1][tid];
}

// ---------------------------------------------------------------------------
// K2: softmax over the N (titles) axis, per (b,t).
// ---------------------------------------------------------------------------
__global__ void k2_softmax_n(const float* __restrict__ score, float* __restrict__ alpha) {
  int i = blockIdx.x * 256 + threadIdx.x;
  if (i >= BB * TT) return;
  int b = i / TT, t = i - b * TT;
  int base = b * (NN * TT) + t;
  float m = -1e30f;
  for (int n = 0; n < NN; ++n) m = fmaxf(m, score[base + n * TT]);
  float s = 0.f;
  for (int n = 0; n < NN; ++n) s += __expf(score[base + n * TT] - m);
  float inv = 1.f / s;
  for (int n = 0; n < NN; ++n)
    alpha[base + n * TT] = __expf(score[base + n * TT] - m) * inv;
}

// ---------------------------------------------------------------------------
// K3: e[bn,f] = sum_t alpha[bn,t] * C[bn,t,f]  -> bf16 [3200][416] padded
// ---------------------------------------------------------------------------
__global__ __launch_bounds__(256) void k3_wsum(
    const float* __restrict__ alpha, const __hip_bfloat16* __restrict__ C,
    __hip_bfloat16* __restrict__ Ebf) {
  __shared__ float al[TT];
  const int bn = blockIdx.x;
  const int tid = threadIdx.x;
  if (tid < TT) al[tid] = alpha[bn * TT + tid];
  __syncthreads();
  for (int f = tid; f < 416; f += 256) {
    float s = 0.f;
    if (f < FN) {
#pragma unroll
      for (int t = 0; t < TT; ++t)
        s = fmaf(al[t], __bfloat162float(C[((size_t)bn * TT + t) * 416 + f]), s);
    }
    Ebf[(size_t)bn * 416 + f] = __float2bfloat16(s);
  }
}

// ---------------------------------------------------------------------------
// K4: gx = e @ W_ih^T + b_ih via bf16 MFMA. M=3200, N=1344(pad), K=416.
// ---------------------------------------------------------------------------
__global__ __launch_bounds__(512) void k4_gx_mfma(
    const __hip_bfloat16* __restrict__ Ebf,   // [3200][416]
    const __hip_bfloat16* __restrict__ Wih,   // [1344][416]
    const float* __restrict__ b_ih,           // [1200]
    float* __restrict__ gx)                   // [3200][1200]
{
  __shared__ __align__(16) ushort Alds[128 * 40];
  __shared__ __align__(16) ushort Blds[448 * 40];
  const int tid = threadIdx.x;
  const int lane = tid & 63, wid = tid >> 6;
  const int wm = wid >> 2, wn = wid & 3;
  const int l15 = lane & 15, l4 = lane >> 4;
  const int mb = blockIdx.x / 3;
  const int nb = blockIdx.x - mb * 3;
  const int row0 = mb * 128;
  const int n0 = nb * 448;

  f32x4 acc[4][7];
#pragma unroll
  for (int nt = 0; nt < 7; ++nt) {
    int j = n0 + wn * 112 + nt * 16 + l15;
    float bj = (j < 1200) ? b_ih[j] : 0.f;
#pragma unroll
    for (int mt = 0; mt < 4; ++mt) {
      acc[mt][nt][0] = bj; acc[mt][nt][1] = bj;
      acc[mt][nt][2] = bj; acc[mt][nt][3] = bj;
    }
  }

  const int ar = tid >> 2, ac = tid & 3;
  for (int ks = 0; ks < 13; ++ks) {
    *(uint4*)(&Alds[ar * 40 + ac * 8]) =
        *(const uint4*)((const ushort*)Ebf + (size_t)(row0 + ar) * 416 + ks * 32 + ac * 8);
    for (int idx = tid; idx < 1792; idx += 512) {
      int r = idx >> 2, c = idx & 3;
      *(uint4*)(&Blds[r * 40 + c * 8]) =
          *(const uint4*)((const ushort*)Wih + (size_t)(n0 + r) * 416 + ks * 32 + c * 8);
    }
    __syncthreads();
    bf16x8 af[4];
#pragma unroll
    for (int mt = 0; mt < 4; ++mt)
      af[mt] = *(const bf16x8*)(&Alds[(wm * 64 + mt * 16 + l15) * 40 + l4 * 8]);
#pragma unroll
    for (int nt = 0; nt < 7; ++nt) {
      bf16x8 bfr = *(const bf16x8*)(&Blds[(wn * 112 + nt * 16 + l15) * 40 + l4 * 8]);
#pragma unroll
      for (int mt = 0; mt < 4; ++mt)
        acc[mt][nt] = __builtin_amdgcn_mfma_f32_16x16x32_bf16(af[mt], bfr, acc[mt][nt], 0, 0, 0);
    }
    __syncthreads();
  }

#pragma unroll
  for (int mt = 0; mt < 4; ++mt) {
    int row = row0 + wm * 64 + mt * 16 + l4 * 4;
#pragma unroll
    for (int nt = 0; nt < 7; ++nt) {
      int j = n0 + wn * 112 + nt * 16 + l15;
      if (j < 1200) {
#pragma unroll
        for (int r = 0; r < 4; ++r)
          gx[(size_t)(row + r) * 1200 + j] = acc[mt][nt][r];
      }
    }
  }
}

// ---------------------------------------------------------------------------
// GRU: 50-launch chain (grid.sync measured 7x slower on this chip — per-XCD
// L2 non-coherence makes device-scope fences cost ~35us/step at 256 blocks).
// ---------------------------------------------------------------------------
__global__ void k5_init(const int* __restrict__ user_id,
                        const float* __restrict__ user_emb,
                        float* __restrict__ h0) {
  int idx = blockIdx.x * 256 + threadIdx.x;
  if (idx < BB * GG) {
    int b = idx / GG, g = idx - b * GG;
    h0[idx] = user_emb[(long)user_id[b] * GG + g];
  }
}

__global__ __launch_bounds__(256) void k5_step(
    const float* __restrict__ h_prev, float* __restrict__ h_next,
    const float* __restrict__ Wpack, const float* __restrict__ b_hh,
    const float* __restrict__ gx, const int* __restrict__ hist_len, int step)
{
  const int gc = blockIdx.x & 7;
  const int bg = blockIdx.x >> 3;
  const int tid = threadIdx.x;
  __shared__ float hl[2][GG];
  __shared__ float ghl[2][3][50];

  for (int i = tid; i < 2 * GG; i += 256) {
    int b = i / GG, g = i - b * GG;
    hl[b][g] = h_prev[(2 * bg + b) * GG + g];
  }
  __syncthreads();

  if (tid < 150) {
    float acc0 = 0.f, acc1 = 0.f;
    const float* wp = Wpack + (size_t)gc * 400 * 150 + tid;
#pragma unroll 8
    for (int g = 0; g < GG; ++g) {
      float w = wp[g * 150];
      acc0 = fmaf(hl[0][g], w, acc0);
      acc1 = fmaf(hl[1][g], w, acc1);
    }
    int gate = tid / 50, gl = tid - gate * 50;
    float bb = b_hh[gate * 400 + gc * 50 + gl];
    ghl[0][gate][gl] = acc0 + bb;
    ghl[1][gate][gl] = acc1 + bb;
  }
  __syncthreads();

  if (tid < 100) {
    int b = tid / 50, gl = tid - (tid / 50) * 50;
    int babs = 2 * bg + b;
    int g = gc * 50 + gl;
    const float* gxp = gx + ((size_t)babs * NN + step) * 1200;
    float xr = gxp[g], xz = gxp[400 + g], xn = gxp[800 + g];
    float hr = ghl[b][0][gl], hz = ghl[b][1][gl], hn = ghl[b][2][gl];
    float r = 1.f / (1.f + __expf(-(xr + hr)));
    float z = 1.f / (1.f + __expf(-(xz + hz)));
    float nv = tanhf(xn + r * hn);
    float hold = hl[b][g];
    float hnew = (1.f - z) * nv + z * hold;
    h_next[babs * GG + g] = (step < hist_len[babs]) ? hnew : hold;
  }
}

__global__ void k5_out(const float* __restrict__ h, float* __restrict__ out) {
  int idx = blockIdx.x * 256 + threadIdx.x;
  if (idx < BB * GG) out[idx] = h[idx];
}

// ---------------------------------------------------------------------------
extern "C" void kernel_launch(void* const* d_in, const int* in_sizes, int n_in,
                              void* d_out, int out_size, void* d_ws, size_t ws_size,
                              hipStream_t stream) {
  const int*   user_id   = (const int*)d_in[0];
  const int*   title     = (const int*)d_in[1];
  const int*   hist_len  = (const int*)d_in[2];
  const float* word_emb  = (const float*)d_in[3];
  const float* conv_w    = (const float*)d_in[4];
  const float* conv_b    = (const float*)d_in[5];
  const float* v         = (const float*)d_in[6];
  const float* vb        = (const float*)d_in[7];
  const float* q         = (const float*)d_in[8];
  const float* user_emb  = (const float*)d_in[9];
  const float* W_ih      = (const float*)d_in[10];
  const float* W_hh      = (const float*)d_in[11];
  const float* b_ih      = (const float*)d_in[12];
  const float* b_hh      = (const float*)d_in[13];
  float* out = (float*)d_out;

  char* ws = (char*)d_ws;
  size_t off = 0;
  auto take = [&](size_t bytes) {
    char* p = ws + off;
    off = (off + bytes + 255) & ~(size_t)255;
    return p;
  };
  __hip_bfloat16* C      = (__hip_bfloat16*)take((size_t)BB * NN * TT * 416 * 2);  // 79.9MB
  float* score  = (float*)take((size_t)BB * NN * TT * 4);
  float* alpha  = (float*)take((size_t)BB * NN * TT * 4);
  __hip_bfloat16* Ebf    = (__hip_bfloat16*)take((size_t)BB * NN * 416 * 2);
  __hip_bfloat16* Wih_bf = (__hip_bfloat16*)take((size_t)1344 * 416 * 2);
  float* Wpack  = (float*)take((size_t)8 * 400 * 150 * 4);
  float* gx     = (float*)take((size_t)BB * NN * 1200 * 4);
  float* h0     = (float*)take((size_t)BB * GG * 4);
  float* h1     = (float*)take((size_t)BB * GG * 4);
  __hip_bfloat16* emb_bf = (__hip_bfloat16*)take((size_t)50000 * 320 * 2);        // 32MB
  __hip_bfloat16* WT2    = (__hip_bfloat16*)take((size_t)30 * 448 * 32 * 2);      // 860KB
  __hip_bfloat16* vT     = (__hip_bfloat16*)take((size_t)224 * 416 * 2);
  float* qp     = (float*)take(224 * 4);
  float* vbp    = (float*)take(224 * 4);
  (void)ws_size;

  k_pack_whh<<<(8 * 400 * 150 + 255) / 256, 256, 0, stream>>>(W_hh, Wpack);
  k_prep_emb<<<(50000 * 320 + 255) / 256, 256, 0, stream>>>(word_emb, emb_bf);
  k_prep_wt2<<<(30 * 448 * 32 + 255) / 256, 256, 0, stream>>>(conv_w, WT2);
  k_prep_v<<<(224 * 416 + 255) / 256, 256, 0, stream>>>(v, vT);
  k_prep_qvb<<<1, 256, 0, stream>>>(q, vb, qp, vbp);
  k_prep_wih<<<(1344 * 416 + 255) / 256, 256, 0, stream>>>(W_ih, Wih_bf);

  k_conv<<<BB * NN / 2, 256, 0, stream>>>(title, emb_bf, WT2, conv_b, C);
  k_attn<<<BB * NN * TT / 256, 512, 0, stream>>>(C, vT, vbp, qp, score);
  k2_softmax_n<<<(BB * TT + 255) / 256, 256, 0, stream>>>(score, alpha);
  k3_wsum<<<BB * NN, 256, 0, stream>>>(alpha, C, Ebf);
  k4_gx_mfma<<<75, 512, 0, stream>>>(Ebf, Wih_bf, b_ih, gx);

  k5_init<<<(BB * GG + 255) / 256, 256, 0, stream>>>(user_id, user_emb, h0);
  float* hbuf[2] = {h0, h1};
  for (int step = 0; step < NN; ++step) {
    k5_step<<<256, 256, 0, stream>>>(hbuf[step & 1], hbuf[(step + 1) & 1],
                                     Wpack, b_hh, gx, hist_len, step);
  }
  k5_out<<<(BB * GG + 255) / 256, 256, 0, stream>>>(h0, out);
}